// Round 4
// baseline (122.546 us; speedup 1.0000x reference)
//
#include <hip/hip_runtime.h>
#include <math.h>

typedef unsigned short u16;
typedef unsigned int u32;
typedef __attribute__((ext_vector_type(8))) __bf16 bf16x8;
typedef __attribute__((ext_vector_type(4))) float f32x4;

// ---------- helpers ----------

__device__ __forceinline__ u16 f2bf(float x) {
    __bf16 h = (__bf16)x;                 // fptrunc = round-to-nearest-even
    return __builtin_bit_cast(u16, h);
}

// order-preserving float -> uint mapping (monotonic), for atomicMax on floats
__device__ __forceinline__ u32 ordf(float f) {
    u32 u = __float_as_uint(f);
    return (u & 0x80000000u) ? ~u : (u | 0x80000000u);
}
__device__ __forceinline__ float unordf(u32 u) {
    u = (u & 0x80000000u) ? (u & 0x7FFFFFFFu) : ~u;
    return __uint_as_float(u);
}

// async global->LDS, 16B per lane (dest = wave-uniform base + lane*16)
__device__ __forceinline__ void gload_lds16(const void* gsrc, void* ldst) {
    __builtin_amdgcn_global_load_lds(
        (const __attribute__((address_space(1))) void*)gsrc,
        (__attribute__((address_space(3))) void*)ldst,
        16, 0, 0);
}

#define BARRIER do { __builtin_amdgcn_sched_barrier(0); \
                     __builtin_amdgcn_s_barrier(); \
                     __builtin_amdgcn_sched_barrier(0); } while (0)
#define VMCNT(n) do { asm volatile("s_waitcnt vmcnt(" #n ")" ::: "memory"); \
                      __builtin_amdgcn_sched_barrier(0); } while (0)

// ---------- kernel 1: normalize rows, convert to bf16; init rowmax ----------

__global__ __launch_bounds__(256) void norm_kernel(
    const float* __restrict__ feat, const float* __restrict__ memf,
    u16* __restrict__ fb, u16* __restrict__ mb, u32* __restrict__ rowmax,
    int N, int M, int D)
{
    const int lane = threadIdx.x & 63;
    const int wid  = threadIdx.x >> 6;
    const int rid  = blockIdx.x * 4 + wid;
    if (rid >= N + M) return;

    const float* src;
    u16* dst;
    if (rid < N) { src = feat + (size_t)rid * D; dst = fb + (size_t)rid * D; }
    else         { src = memf + (size_t)(rid - N) * D; dst = mb + (size_t)(rid - N) * D; }

    float4 v0 = *(const float4*)(src + lane * 8);
    float4 v1 = *(const float4*)(src + lane * 8 + 4);
    float ss = v0.x*v0.x + v0.y*v0.y + v0.z*v0.z + v0.w*v0.w
             + v1.x*v1.x + v1.y*v1.y + v1.z*v1.z + v1.w*v1.w;
    #pragma unroll
    for (int m = 1; m <= 32; m <<= 1) ss += __shfl_xor(ss, m);

    float inv = 1.0f / fmaxf(sqrtf(ss), 1e-8f);

    u16 o[8];
    o[0] = f2bf(v0.x * inv); o[1] = f2bf(v0.y * inv);
    o[2] = f2bf(v0.z * inv); o[3] = f2bf(v0.w * inv);
    o[4] = f2bf(v1.x * inv); o[5] = f2bf(v1.y * inv);
    o[6] = f2bf(v1.z * inv); o[7] = f2bf(v1.w * inv);
    *(uint4*)(dst + lane * 8) = *(const uint4*)o;

    if (rid < N && lane == 0) rowmax[rid] = 0u;   // below any real sim
}

// ---------- kernel 2: 256x256x(BK=64) software-pipelined GEMM + fused row-max --
// 8 waves (2M x 4N), per-wave output 128x64 = acc[8][4] 16x16 fragments.
// LDS 128KB: A[2][256][64] bf16 @0, B[2][256][64] @64KB. XOR-swizzled rows.
// Snake quads: p0:Q(0,0) p1:Q(0,1) p2:Q(1,1) p3:Q(1,0).
// ds_reads issued ONE PHASE AHEAD of use (4/8/4/8 per phase); NO lgkmcnt(0) —
// compiler's counted lgkm handles RAW; reads drain under the current MFMA.
// Staging (2 tiles ahead): p2: h2(u+2); p3: h0,h1,h3(u+2).
// VMCNT(2) at p2 (after h2-stage) guarantees tile u+1 fully resident before
// its first ds_read (b0n at p2, a0 at p3). One barrier per phase end.

#define STAGE(t, h) do { \
    const u16* gsrc_ = ((h) < 2) ? gA : gB; \
    const int base_ = (((h) < 2) ? 0 : 32768) + (((t) & 1) * 16384) + (((h) & 1) * 8192); \
    const size_t go_ = (size_t)(((h) & 1) * 128) * D + (size_t)(t) * 64; \
    gload_lds16(gsrc_ + go_,                  &L[base_ + tid * 8]); \
    gload_lds16(gsrc_ + go_ + (size_t)64 * D, &L[base_ + 4096 + tid * 8]); \
  } while (0)

#define MFMA_QUAD(RS, CS) do { \
    _Pragma("unroll") \
    for (int i_ = 0; i_ < 4; ++i_) \
      _Pragma("unroll") \
      for (int j_ = 0; j_ < 2; ++j_) \
        _Pragma("unroll") \
        for (int k_ = 0; k_ < 2; ++k_) \
          acc[(RS)*4 + i_][(CS)*2 + j_] = __builtin_amdgcn_mfma_f32_16x16x32_bf16( \
              a[RS][i_][k_], b[CS][j_][k_], acc[(RS)*4 + i_][(CS)*2 + j_], 0, 0, 0); \
  } while (0)

__global__ __launch_bounds__(512, 2) void gemm_max_kernel(
    const u16* __restrict__ fb, const u16* __restrict__ mb,
    u32* __restrict__ rowmax, int N, int M, int D)
{
    __shared__ __align__(16) u16 L[65536];   // 128 KB

    const int tid  = threadIdx.x;
    const int lane = tid & 63;
    const int wid  = tid >> 6;
    const int wr   = wid >> 2;      // 0..1
    const int wc   = wid & 3;       // 0..3
    const int l15  = lane & 15;
    const int l4   = lane >> 4;
    const int n0   = blockIdx.y * 256;
    const int m0   = blockIdx.x * 256;
    const int nt   = D >> 6;        // 8 K-tiles

    // staging: per-thread pre-swizzled global bases (row = t8, chunk = tid&7)
    const int t8   = tid >> 3;
    const int swz8 = ((tid & 7) ^ (t8 & 7)) * 8;
    const u16* gA = fb + (size_t)(n0 + t8) * D + swz8;
    const u16* gB = mb + (size_t)(m0 + t8) * D + swz8;

    // ds_read: per-thread swizzled k-offsets
    const int s   = (l15 & 7) << 4;
    const int oA0 = (l4 * 16) ^ s;
    const int oA1 = (64 + l4 * 16) ^ s;
    const int arow = (wr * 128 + l15) * 128;   // byte row base in A space
    const int brow = (wc * 64 + l15) * 128;    // byte row base in B space
    const char* Lb = (const char*)L;

    f32x4 acc[8][4] = {};
    bf16x8 a[2][4][2], b[2][2][2], b0n[2][2];

    // ---- prologue: tile0 (h2,h0,h1,h3) + tile1 h2; wait; read b0(0);
    //      tile1 h0,h1,h3; read a0(0) ----
    STAGE(0, 2); STAGE(0, 0); STAGE(0, 1); STAGE(0, 3);
    if (nt > 1) { STAGE(1, 2); VMCNT(2); } else { VMCNT(0); }
    {
        const char* pb0 = Lb + 65536 + brow + oA0;
        const char* pb1 = Lb + 65536 + brow + oA1;
        #pragma unroll
        for (int j = 0; j < 2; ++j) {
            b[0][j][0] = *(const bf16x8*)(pb0 + j * 2048);
            b[0][j][1] = *(const bf16x8*)(pb1 + j * 2048);
        }
    }
    if (nt > 1) { STAGE(1, 0); STAGE(1, 1); STAGE(1, 3); }
    {
        const char* pa0 = Lb + arow + oA0;
        const char* pa1 = Lb + arow + oA1;
        #pragma unroll
        for (int i = 0; i < 4; ++i) {
            a[0][i][0] = *(const bf16x8*)(pa0 + i * 2048);
            a[0][i][1] = *(const bf16x8*)(pa1 + i * 2048);
        }
    }
    BARRIER;

    for (int u = 0; u < nt; ++u) {
        const int cb = (u & 1) * 32768;
        const int nb = 32768 - cb;
        const char* pa0 = Lb + cb + arow + oA0;
        const char* pa1 = Lb + cb + arow + oA1;
        const char* pb0 = Lb + 65536 + cb + brow + oA0;
        const char* pb1 = Lb + 65536 + cb + brow + oA1;
        const char* qa0 = Lb + nb + arow + oA0;
        const char* qa1 = Lb + nb + arow + oA1;
        const char* qb0 = Lb + 65536 + nb + brow + oA0;
        const char* qb1 = Lb + 65536 + nb + brow + oA1;

        // ---- p0: read b1(u); MFMA Q(0,0) [a0,b0] ----
        #pragma unroll
        for (int j = 0; j < 2; ++j) {
            b[1][j][0] = *(const bf16x8*)(pb0 + (2 + j) * 2048);
            b[1][j][1] = *(const bf16x8*)(pb1 + (2 + j) * 2048);
        }
        __builtin_amdgcn_s_setprio(1);
        MFMA_QUAD(0, 0);
        __builtin_amdgcn_s_setprio(0);
        BARRIER;

        // ---- p1: read a1(u); MFMA Q(0,1) [a0,b1] ----
        #pragma unroll
        for (int i = 0; i < 4; ++i) {
            a[1][i][0] = *(const bf16x8*)(pa0 + (4 + i) * 2048);
            a[1][i][1] = *(const bf16x8*)(pa1 + (4 + i) * 2048);
        }
        __builtin_amdgcn_s_setprio(1);
        MFMA_QUAD(0, 1);
        __builtin_amdgcn_s_setprio(0);
        BARRIER;

        // ---- p2: stage h2(u+2); vmcnt; read b0n(u+1); MFMA Q(1,1) [a1,b1] ----
        if (u + 1 < nt) {
            if (u + 2 < nt) { STAGE(u + 2, 2); VMCNT(2); }
            else            { VMCNT(0); }
            #pragma unroll
            for (int j = 0; j < 2; ++j) {
                b0n[j][0] = *(const bf16x8*)(qb0 + j * 2048);
                b0n[j][1] = *(const bf16x8*)(qb1 + j * 2048);
            }
        }
        __builtin_amdgcn_s_setprio(1);
        MFMA_QUAD(1, 1);
        __builtin_amdgcn_s_setprio(0);
        BARRIER;

        // ---- p3: stage h0,h1,h3(u+2); read a0(u+1); MFMA Q(1,0) [a1,b0];
        //      then b0 <= b0n ----
        if (u + 2 < nt) { STAGE(u + 2, 0); STAGE(u + 2, 1); STAGE(u + 2, 3); }
        if (u + 1 < nt) {
            #pragma unroll
            for (int i = 0; i < 4; ++i) {
                a[0][i][0] = *(const bf16x8*)(qa0 + i * 2048);
                a[0][i][1] = *(const bf16x8*)(qa1 + i * 2048);
            }
        }
        __builtin_amdgcn_s_setprio(1);
        MFMA_QUAD(1, 0);
        __builtin_amdgcn_s_setprio(0);
        if (u + 1 < nt) {
            #pragma unroll
            for (int j = 0; j < 2; ++j) {
                b[0][j][0] = b0n[j][0];
                b[0][j][1] = b0n[j][1];
            }
        }
        BARRIER;
    }

    // ---- epilogue: per-row max; cross-wave LDS reduce; one atomic/row ----
    float* red = (float*)L;   // [256][4]
    #pragma unroll
    for (int i = 0; i < 8; ++i) {
        #pragma unroll
        for (int rr = 0; rr < 4; ++rr) {
            float v = fmaxf(fmaxf(acc[i][0][rr], acc[i][1][rr]),
                            fmaxf(acc[i][2][rr], acc[i][3][rr]));
            v = fmaxf(v, __shfl_xor(v, 1));
            v = fmaxf(v, __shfl_xor(v, 2));
            v = fmaxf(v, __shfl_xor(v, 4));
            v = fmaxf(v, __shfl_xor(v, 8));
            if (l15 == 0) {
                int rloc = wr * 128 + i * 16 + l4 * 4 + rr;
                red[rloc * 4 + wc] = v;
            }
        }
    }
    __syncthreads();
    if (tid < 256) {
        float v = fmaxf(fmaxf(red[tid * 4 + 0], red[tid * 4 + 1]),
                        fmaxf(red[tid * 4 + 2], red[tid * 4 + 3]));
        atomicMax(&rowmax[n0 + tid], ordf(v));
    }
}

// ---------- kernel 3: BCE + novelty weight + mean ----------

__global__ __launch_bounds__(1024) void finalize_kernel(
    const float* __restrict__ pred, const float* __restrict__ targ,
    const u32* __restrict__ rowmax, float* __restrict__ out, int N)
{
    __shared__ float wsum[16];
    const int tid = threadIdx.x;
    const int lane = tid & 63;
    const int wid = tid >> 6;

    float sacc = 0.f;
    for (int i = tid; i < N; i += 1024) {
        float x = pred[i];
        float t = targ[i];
        float bl = fmaxf(x, 0.f) + log1pf(expf(-fabsf(x))) - x * t;  // softplus(x) - x*t
        float ms = unordf(rowmax[i]);
        float w = 1.0f + 2.0f * (1.0f - ms);
        sacc += bl * w;
    }
    #pragma unroll
    for (int m = 1; m <= 32; m <<= 1) sacc += __shfl_xor(sacc, m);
    if (lane == 0) wsum[wid] = sacc;
    __syncthreads();
    if (tid < 16) {
        float t = wsum[tid];
        t += __shfl_xor(t, 1);
        t += __shfl_xor(t, 2);
        t += __shfl_xor(t, 4);
        t += __shfl_xor(t, 8);
        if (tid == 0) out[0] = t / (float)N;
    }
}

// ---------- launch ----------

extern "C" void kernel_launch(void* const* d_in, const int* in_sizes, int n_in,
                              void* d_out, int out_size, void* d_ws, size_t ws_size,
                              hipStream_t stream) {
    const float* pred = (const float*)d_in[0];
    const float* targ = (const float*)d_in[1];
    const float* feat = (const float*)d_in[2];
    const float* memf = (const float*)d_in[3];
    const int N = in_sizes[0];
    const int D = in_sizes[2] / N;
    const int M = in_sizes[3] / D;
    float* out = (float*)d_out;

    u16* fb = (u16*)d_ws;                          // N*D bf16
    u16* mb = fb + (size_t)N * D;                  // M*D bf16
    u32* rowmax = (u32*)(mb + (size_t)M * D);      // N u32

    const int rows = N + M;
    norm_kernel<<<dim3((rows + 3) / 4), dim3(256), 0, stream>>>(
        feat, memf, fb, mb, rowmax, N, M, D);
    gemm_max_kernel<<<dim3(M / 256, N / 256), dim3(512), 0, stream>>>(
        fb, mb, rowmax, N, M, D);
    finalize_kernel<<<dim3(1), dim3(1024), 0, stream>>>(pred, targ, rowmax, out, N);
}

// Round 5
// 105.833 us; speedup vs baseline: 1.1579x; 1.1579x over previous
//
#include <hip/hip_runtime.h>
#include <math.h>

typedef unsigned short u16;
typedef unsigned int u32;
typedef __attribute__((ext_vector_type(8))) __bf16 bf16x8;
typedef __attribute__((ext_vector_type(4))) float f32x4;

// ---------- helpers ----------

__device__ __forceinline__ u16 f2bf(float x) {
    __bf16 h = (__bf16)x;                 // fptrunc = round-to-nearest-even
    return __builtin_bit_cast(u16, h);
}

// order-preserving float -> uint mapping (monotonic), for atomicMax on floats
__device__ __forceinline__ u32 ordf(float f) {
    u32 u = __float_as_uint(f);
    return (u & 0x80000000u) ? ~u : (u | 0x80000000u);
}
__device__ __forceinline__ float unordf(u32 u) {
    u = (u & 0x80000000u) ? (u & 0x7FFFFFFFu) : ~u;
    return __uint_as_float(u);
}

// async global->LDS, 16B per lane (dest = wave-uniform base + lane*16)
__device__ __forceinline__ void gload_lds16(const void* gsrc, void* ldst) {
    __builtin_amdgcn_global_load_lds(
        (const __attribute__((address_space(1))) void*)gsrc,
        (__attribute__((address_space(3))) void*)ldst,
        16, 0, 0);
}

#define BARRIER do { __builtin_amdgcn_sched_barrier(0); \
                     __builtin_amdgcn_s_barrier(); \
                     __builtin_amdgcn_sched_barrier(0); } while (0)
#define VMCNT(n) do { asm volatile("s_waitcnt vmcnt(" #n ")" ::: "memory"); \
                      __builtin_amdgcn_sched_barrier(0); } while (0)
#define LGKMC(n) do { asm volatile("s_waitcnt lgkmcnt(" #n ")" ::: "memory"); \
                      __builtin_amdgcn_sched_barrier(0); } while (0)

// ---------- kernel 1: normalize rows, convert to bf16; init rowmax ----------

__global__ __launch_bounds__(256) void norm_kernel(
    const float* __restrict__ feat, const float* __restrict__ memf,
    u16* __restrict__ fb, u16* __restrict__ mb, u32* __restrict__ rowmax,
    int N, int M, int D)
{
    const int lane = threadIdx.x & 63;
    const int wid  = threadIdx.x >> 6;
    const int rid  = blockIdx.x * 4 + wid;
    if (rid >= N + M) return;

    const float* src;
    u16* dst;
    if (rid < N) { src = feat + (size_t)rid * D; dst = fb + (size_t)rid * D; }
    else         { src = memf + (size_t)(rid - N) * D; dst = mb + (size_t)(rid - N) * D; }

    float4 v0 = *(const float4*)(src + lane * 8);
    float4 v1 = *(const float4*)(src + lane * 8 + 4);
    float ss = v0.x*v0.x + v0.y*v0.y + v0.z*v0.z + v0.w*v0.w
             + v1.x*v1.x + v1.y*v1.y + v1.z*v1.z + v1.w*v1.w;
    #pragma unroll
    for (int m = 1; m <= 32; m <<= 1) ss += __shfl_xor(ss, m);

    float inv = 1.0f / fmaxf(sqrtf(ss), 1e-8f);

    u16 o[8];
    o[0] = f2bf(v0.x * inv); o[1] = f2bf(v0.y * inv);
    o[2] = f2bf(v0.z * inv); o[3] = f2bf(v0.w * inv);
    o[4] = f2bf(v1.x * inv); o[5] = f2bf(v1.y * inv);
    o[6] = f2bf(v1.z * inv); o[7] = f2bf(v1.w * inv);
    *(uint4*)(dst + lane * 8) = *(const uint4*)o;

    if (rid < N && lane == 0) rowmax[rid] = 0u;   // below any real sim
}

// ---------- kernel 2: 256x256x(BK=64) counted-lgkm pipelined GEMM + row-max ----
// 8 waves (2M x 4N), per-wave 128x64 output = acc[8][4]. LDS 128KB dbuf,
// XOR-swizzled rows (byte ^= (row&7)<<4), linear gload_lds dest.
// Snake quads: p0:Q00(a0,b0) p1:Q01(a0,b1) p2:Q11(a1,b1) p3:Q10(a1,b0).
// Reads ONE PHASE AHEAD with COUNTED lgkm gates (gate = #reads this phase),
// so each phase's reads drain UNDER its MFMA cluster:
//   p0: read b1(u)[4], gate lgkm(4);  p1: read a1(u)[8], gate lgkm(8);
//   p2: gate lgkm(0);                 p3: after Q10, read b0,a0(u+1)[12].
// Stage ledger (r3, 3-phase headroom): p0:h3(u+1); p2:h2(u+2); p3:h0,h1(u+2).
// VMCNT(2) at p3-START: 10 outstanding (h2(u+1)2, h0h1(u+1)4, h3(u+1)2,
// h2(u+2)2) -> drains all 8 of tile u+1, leaves h2(u+2). WAR per half verified:
// every read of a slot is lgkm-certified before a barrier that precedes the
// slot's next stage. One barrier per phase.

#define STAGE(t, h) do { \
    const u16* gsrc_ = ((h) < 2) ? gA : gB; \
    const int base_ = (((h) < 2) ? 0 : 32768) + (((t) & 1) * 16384) + (((h) & 1) * 8192); \
    const size_t go_ = (size_t)(((h) & 1) * 128) * D + (size_t)(t) * 64; \
    gload_lds16(gsrc_ + go_,                  &L[base_ + tid * 8]); \
    gload_lds16(gsrc_ + go_ + (size_t)64 * D, &L[base_ + 4096 + tid * 8]); \
  } while (0)

#define MFMA_QUAD(RS, CS) do { \
    _Pragma("unroll") \
    for (int i_ = 0; i_ < 4; ++i_) \
      _Pragma("unroll") \
      for (int j_ = 0; j_ < 2; ++j_) \
        _Pragma("unroll") \
        for (int k_ = 0; k_ < 2; ++k_) \
          acc[(RS)*4 + i_][(CS)*2 + j_] = __builtin_amdgcn_mfma_f32_16x16x32_bf16( \
              a[RS][i_][k_], b[CS][j_][k_], acc[(RS)*4 + i_][(CS)*2 + j_], 0, 0, 0); \
  } while (0)

__global__ __launch_bounds__(512, 2) void gemm_max_kernel(
    const u16* __restrict__ fb, const u16* __restrict__ mb,
    u32* __restrict__ rowmax, int N, int M, int D)
{
    __shared__ __align__(16) u16 L[65536];   // 128 KB

    const int tid  = threadIdx.x;
    const int lane = tid & 63;
    const int wid  = tid >> 6;
    const int wr   = wid >> 2;      // 0..1
    const int wc   = wid & 3;       // 0..3
    const int l15  = lane & 15;
    const int l4   = lane >> 4;
    const int nt   = D >> 6;        // K-tiles

    // T1: XCD-aware block swizzle (valid when nwg % 8 == 0)
    const int mt   = M >> 8;        // tiles along M
    const int nwg  = (N >> 8) * mt;
    int bid = blockIdx.x;
    if ((nwg & 7) == 0) bid = (bid & 7) * (nwg >> 3) + (bid >> 3);
    const int n0 = (bid / mt) << 8;
    const int m0 = (bid % mt) << 8;

    // staging: per-thread pre-swizzled global bases (row = t8, chunk = tid&7)
    const int t8   = tid >> 3;
    const int swz8 = ((tid & 7) ^ (t8 & 7)) * 8;
    const u16* gA = fb + (size_t)(n0 + t8) * D + swz8;
    const u16* gB = mb + (size_t)(m0 + t8) * D + swz8;

    // ds_read: per-thread swizzled k-offsets
    const int s   = (l15 & 7) << 4;
    const int oA0 = (l4 * 16) ^ s;
    const int oA1 = (64 + l4 * 16) ^ s;
    const int arow = (wr * 128 + l15) * 128;   // byte row base in A space
    const int brow = (wc * 64 + l15) * 128;    // byte row base in B space
    const char* Lb = (const char*)L;

    f32x4 acc[8][4] = {};
    bf16x8 a[2][4][2], b[2][2][2];

    // ---- prologue: t0 full (8) + t1 h2 (2); drain t0; t1 h0,h1; read b0,a0(0)
    STAGE(0, 2); STAGE(0, 0); STAGE(0, 1); STAGE(0, 3);
    if (nt > 1) { STAGE(1, 2); VMCNT(2); } else { VMCNT(0); }
    if (nt > 1) { STAGE(1, 0); STAGE(1, 1); }
    {
        const char* pb0 = Lb + 65536 + brow + oA0;
        const char* pb1 = Lb + 65536 + brow + oA1;
        #pragma unroll
        for (int j = 0; j < 2; ++j) {
            b[0][j][0] = *(const bf16x8*)(pb0 + j * 2048);
            b[0][j][1] = *(const bf16x8*)(pb1 + j * 2048);
        }
        const char* pa0 = Lb + arow + oA0;
        const char* pa1 = Lb + arow + oA1;
        #pragma unroll
        for (int i = 0; i < 4; ++i) {
            a[0][i][0] = *(const bf16x8*)(pa0 + i * 2048);
            a[0][i][1] = *(const bf16x8*)(pa1 + i * 2048);
        }
    }
    BARRIER;

    for (int u = 0; u < nt; ++u) {
        const int cb = (u & 1) * 32768;
        const int nb = 32768 - cb;
        const char* pa0 = Lb + cb + arow + oA0;
        const char* pa1 = Lb + cb + arow + oA1;
        const char* pb0 = Lb + 65536 + cb + brow + oA0;
        const char* pb1 = Lb + 65536 + cb + brow + oA1;
        const char* qa0 = Lb + nb + arow + oA0;
        const char* qa1 = Lb + nb + arow + oA1;
        const char* qb0 = Lb + 65536 + nb + brow + oA0;
        const char* qb1 = Lb + 65536 + nb + brow + oA1;

        // ---- p0: stage h3(u+1); read b1(u) [4]; gate lgkm(4); Q00(a0,b0) ----
        if (u + 1 < nt) STAGE(u + 1, 3);
        #pragma unroll
        for (int j = 0; j < 2; ++j) {
            b[1][j][0] = *(const bf16x8*)(pb0 + (2 + j) * 2048);
            b[1][j][1] = *(const bf16x8*)(pb1 + (2 + j) * 2048);
        }
        LGKMC(4);
        __builtin_amdgcn_s_setprio(1);
        MFMA_QUAD(0, 0);
        __builtin_amdgcn_s_setprio(0);
        BARRIER;

        // ---- p1: read a1(u) [8]; gate lgkm(8); Q01(a0,b1) ----
        #pragma unroll
        for (int i = 0; i < 4; ++i) {
            a[1][i][0] = *(const bf16x8*)(pa0 + (4 + i) * 2048);
            a[1][i][1] = *(const bf16x8*)(pa1 + (4 + i) * 2048);
        }
        LGKMC(8);
        __builtin_amdgcn_s_setprio(1);
        MFMA_QUAD(0, 1);
        __builtin_amdgcn_s_setprio(0);
        BARRIER;

        // ---- p2: stage h2(u+2); gate lgkm(0); Q11(a1,b1) ----
        if (u + 2 < nt) STAGE(u + 2, 2);
        LGKMC(0);
        __builtin_amdgcn_s_setprio(1);
        MFMA_QUAD(1, 1);
        __builtin_amdgcn_s_setprio(0);
        BARRIER;

        // ---- p3: VMCNT(2) certifies tile u+1; stage h0,h1(u+2); Q10(a1,b0);
        //      then read b0,a0(u+1) from next buffer (drain under next p0) ----
        if (u + 1 < nt) { VMCNT(2); } else { VMCNT(0); }
        if (u + 2 < nt) { STAGE(u + 2, 0); STAGE(u + 2, 1); }
        __builtin_amdgcn_s_setprio(1);
        MFMA_QUAD(1, 0);
        __builtin_amdgcn_s_setprio(0);
        __builtin_amdgcn_sched_barrier(0);
        if (u + 1 < nt) {
            #pragma unroll
            for (int j = 0; j < 2; ++j) {
                b[0][j][0] = *(const bf16x8*)(qb0 + j * 2048);
                b[0][j][1] = *(const bf16x8*)(qb1 + j * 2048);
            }
            #pragma unroll
            for (int i = 0; i < 4; ++i) {
                a[0][i][0] = *(const bf16x8*)(qa0 + i * 2048);
                a[0][i][1] = *(const bf16x8*)(qa1 + i * 2048);
            }
        }
        BARRIER;
    }

    // ---- epilogue: per-row max; cross-wave LDS reduce; one atomic/row ----
    float* red = (float*)L;   // [256][4]
    #pragma unroll
    for (int i = 0; i < 8; ++i) {
        #pragma unroll
        for (int rr = 0; rr < 4; ++rr) {
            float v = fmaxf(fmaxf(acc[i][0][rr], acc[i][1][rr]),
                            fmaxf(acc[i][2][rr], acc[i][3][rr]));
            v = fmaxf(v, __shfl_xor(v, 1));
            v = fmaxf(v, __shfl_xor(v, 2));
            v = fmaxf(v, __shfl_xor(v, 4));
            v = fmaxf(v, __shfl_xor(v, 8));
            if (l15 == 0) {
                int rloc = wr * 128 + i * 16 + l4 * 4 + rr;
                red[rloc * 4 + wc] = v;
            }
        }
    }
    __syncthreads();
    if (tid < 256) {
        float v = fmaxf(fmaxf(red[tid * 4 + 0], red[tid * 4 + 1]),
                        fmaxf(red[tid * 4 + 2], red[tid * 4 + 3]));
        atomicMax(&rowmax[n0 + tid], ordf(v));
    }
}

// ---------- kernel 3: BCE + novelty weight + mean ----------

__global__ __launch_bounds__(1024) void finalize_kernel(
    const float* __restrict__ pred, const float* __restrict__ targ,
    const u32* __restrict__ rowmax, float* __restrict__ out, int N)
{
    __shared__ float wsum[16];
    const int tid = threadIdx.x;
    const int lane = tid & 63;
    const int wid = tid >> 6;

    float sacc = 0.f;
    for (int i = tid; i < N; i += 1024) {
        float x = pred[i];
        float t = targ[i];
        float bl = fmaxf(x, 0.f) + log1pf(expf(-fabsf(x))) - x * t;  // softplus(x) - x*t
        float ms = unordf(rowmax[i]);
        float w = 1.0f + 2.0f * (1.0f - ms);
        sacc += bl * w;
    }
    #pragma unroll
    for (int m = 1; m <= 32; m <<= 1) sacc += __shfl_xor(sacc, m);
    if (lane == 0) wsum[wid] = sacc;
    __syncthreads();
    if (tid < 16) {
        float t = wsum[tid];
        t += __shfl_xor(t, 1);
        t += __shfl_xor(t, 2);
        t += __shfl_xor(t, 4);
        t += __shfl_xor(t, 8);
        if (tid == 0) out[0] = t / (float)N;
    }
}

// ---------- launch ----------

extern "C" void kernel_launch(void* const* d_in, const int* in_sizes, int n_in,
                              void* d_out, int out_size, void* d_ws, size_t ws_size,
                              hipStream_t stream) {
    const float* pred = (const float*)d_in[0];
    const float* targ = (const float*)d_in[1];
    const float* feat = (const float*)d_in[2];
    const float* memf = (const float*)d_in[3];
    const int N = in_sizes[0];
    const int D = in_sizes[2] / N;
    const int M = in_sizes[3] / D;
    float* out = (float*)d_out;

    u16* fb = (u16*)d_ws;                          // N*D bf16
    u16* mb = fb + (size_t)N * D;                  // M*D bf16
    u32* rowmax = (u32*)(mb + (size_t)M * D);      // N u32

    const int rows = N + M;
    const int nblk = (N / 256) * (M / 256);
    norm_kernel<<<dim3((rows + 3) / 4), dim3(256), 0, stream>>>(
        feat, memf, fb, mb, rowmax, N, M, D);
    gemm_max_kernel<<<dim3(nblk), dim3(512), 0, stream>>>(
        fb, mb, rowmax, N, M, D);
    finalize_kernel<<<dim3(1), dim3(1024), 0, stream>>>(pred, targ, rowmax, out, N);
}

// Round 6
// 100.275 us; speedup vs baseline: 1.2221x; 1.0554x over previous
//
#include <hip/hip_runtime.h>
#include <math.h>

typedef unsigned short u16;
typedef unsigned int u32;
typedef __attribute__((ext_vector_type(8))) __bf16 bf16x8;
typedef __attribute__((ext_vector_type(4))) float f32x4;

// ---------- helpers ----------

__device__ __forceinline__ u16 f2bf(float x) {
    __bf16 h = (__bf16)x;                 // fptrunc = round-to-nearest-even
    return __builtin_bit_cast(u16, h);
}

// order-preserving float -> uint mapping (monotonic), for atomicMax on floats
__device__ __forceinline__ u32 ordf(float f) {
    u32 u = __float_as_uint(f);
    return (u & 0x80000000u) ? ~u : (u | 0x80000000u);
}
__device__ __forceinline__ float unordf(u32 u) {
    u = (u & 0x80000000u) ? (u & 0x7FFFFFFFu) : ~u;
    return __uint_as_float(u);
}

// async global->LDS, 16B per lane (dest = wave-uniform base + lane*16)
__device__ __forceinline__ void gload_lds16(const void* gsrc, void* ldst) {
    __builtin_amdgcn_global_load_lds(
        (const __attribute__((address_space(1))) void*)gsrc,
        (__attribute__((address_space(3))) void*)ldst,
        16, 0, 0);
}

#define BARRIER do { __builtin_amdgcn_sched_barrier(0); \
                     __builtin_amdgcn_s_barrier(); \
                     __builtin_amdgcn_sched_barrier(0); } while (0)
#define VMCNT(n) do { asm volatile("s_waitcnt vmcnt(" #n ")" ::: "memory"); \
                      __builtin_amdgcn_sched_barrier(0); } while (0)
#define LGKMC(n) do { asm volatile("s_waitcnt lgkmcnt(" #n ")" ::: "memory"); \
                      __builtin_amdgcn_sched_barrier(0); } while (0)

// ---------- kernel 1: normalize rows, convert to bf16; init rowmax ----------

__global__ __launch_bounds__(256) void norm_kernel(
    const float* __restrict__ feat, const float* __restrict__ memf,
    u16* __restrict__ fb, u16* __restrict__ mb, u32* __restrict__ rowmax,
    int N, int M, int D)
{
    const int lane = threadIdx.x & 63;
    const int wid  = threadIdx.x >> 6;
    const int rid  = blockIdx.x * 4 + wid;
    if (rid >= N + M) return;

    const float* src;
    u16* dst;
    if (rid < N) { src = feat + (size_t)rid * D; dst = fb + (size_t)rid * D; }
    else         { src = memf + (size_t)(rid - N) * D; dst = mb + (size_t)(rid - N) * D; }

    float4 v0 = *(const float4*)(src + lane * 8);
    float4 v1 = *(const float4*)(src + lane * 8 + 4);
    float ss = v0.x*v0.x + v0.y*v0.y + v0.z*v0.z + v0.w*v0.w
             + v1.x*v1.x + v1.y*v1.y + v1.z*v1.z + v1.w*v1.w;
    #pragma unroll
    for (int m = 1; m <= 32; m <<= 1) ss += __shfl_xor(ss, m);

    float inv = 1.0f / fmaxf(sqrtf(ss), 1e-8f);

    u16 o[8];
    o[0] = f2bf(v0.x * inv); o[1] = f2bf(v0.y * inv);
    o[2] = f2bf(v0.z * inv); o[3] = f2bf(v0.w * inv);
    o[4] = f2bf(v1.x * inv); o[5] = f2bf(v1.y * inv);
    o[6] = f2bf(v1.z * inv); o[7] = f2bf(v1.w * inv);
    *(uint4*)(dst + lane * 8) = *(const uint4*)o;

    if (rid < N && lane == 0) rowmax[rid] = 0u;   // below any real sim
}

// ---------- kernel 2: 256x256x(BK=64) one-barrier-per-tile GEMM + row-max ----
// 8 waves (2M x 4N), per-wave 128x64 output = acc[8][4]. LDS 128KB dbuf,
// XOR-swizzled rows (byte ^= (row&7)<<4) via pre-swizzled global source.
// FREE-RUN TILE: one barrier per K-tile; within a tile waves self-de-phase so
// one wave's ds_reads drain under the other SIMD-wave's MFMA cluster.
//   issue b0(4),a0(8),b1(4); stage all 4 halves of u+1 (other buffer);
//   lgkm(4)->Q00(a0,b0); issue a1(8); lgkm(8)->Q01(a0,b1);
//   lgkm(0)->Q11(a1,b1),Q10(a1,b0); vmcnt(0) [stages long done]; barrier.
// WAR: each wave certifies its tile-u reads (lgkm gates) before reaching the
// end-of-tile barrier => stages of u+1 (issued after next barrier) are safe.
// RAW: vmcnt(0)+barrier at tile boundary certifies staged data block-wide.

#define STAGE(t, h) do { \
    const u16* gsrc_ = ((h) < 2) ? gA : gB; \
    const int base_ = (((h) < 2) ? 0 : 32768) + (((t) & 1) * 16384) + (((h) & 1) * 8192); \
    const size_t go_ = (size_t)(((h) & 1) * 128) * D + (size_t)(t) * 64; \
    gload_lds16(gsrc_ + go_,                  &L[base_ + tid * 8]); \
    gload_lds16(gsrc_ + go_ + (size_t)64 * D, &L[base_ + 4096 + tid * 8]); \
  } while (0)

// one quadrant: 4 M-frags x 2 N-frags x 2 k-subs = 16 MFMA
#define QUAD(AR, BR, IO, JO) do { \
    _Pragma("unroll") \
    for (int i_ = 0; i_ < 4; ++i_) \
      _Pragma("unroll") \
      for (int j_ = 0; j_ < 2; ++j_) \
        _Pragma("unroll") \
        for (int k_ = 0; k_ < 2; ++k_) \
          acc[(IO) + i_][(JO) + j_] = __builtin_amdgcn_mfma_f32_16x16x32_bf16( \
              AR[i_][k_], BR[j_][k_], acc[(IO) + i_][(JO) + j_], 0, 0, 0); \
  } while (0)

__global__ __launch_bounds__(512, 2) void gemm_max_kernel(
    const u16* __restrict__ fb, const u16* __restrict__ mb,
    u32* __restrict__ rowmax, int N, int M, int D)
{
    __shared__ __align__(16) u16 L[65536];   // 128 KB

    const int tid  = threadIdx.x;
    const int lane = tid & 63;
    const int wid  = tid >> 6;
    const int wr   = wid >> 2;      // 0..1
    const int wc   = wid & 3;       // 0..3
    const int l15  = lane & 15;
    const int l4   = lane >> 4;
    const int n0   = blockIdx.y * 256;
    const int m0   = blockIdx.x * 256;
    const int nt   = D >> 6;        // K-tiles

    // staging: per-thread pre-swizzled global bases (row = t8, chunk = tid&7)
    const int t8   = tid >> 3;
    const int swz8 = ((tid & 7) ^ (t8 & 7)) * 8;
    const u16* gA = fb + (size_t)(n0 + t8) * D + swz8;
    const u16* gB = mb + (size_t)(m0 + t8) * D + swz8;

    // ds_read: per-thread swizzled k-offsets
    const int s   = (l15 & 7) << 4;
    const int oA0 = (l4 * 16) ^ s;
    const int oA1 = (64 + l4 * 16) ^ s;
    const int arow = (wr * 128 + l15) * 128;   // byte row base in A space
    const int brow = (wc * 64 + l15) * 128;    // byte row base in B space
    const char* Lb = (const char*)L;

    f32x4 acc[8][4] = {};
    bf16x8 a0[4][2], a1[4][2], b0[2][2], b1[2][2];

    // ---- prologue: stage tile0, full drain, barrier ----
    STAGE(0, 0); STAGE(0, 1); STAGE(0, 2); STAGE(0, 3);
    VMCNT(0);
    BARRIER;

    for (int u = 0; u < nt; ++u) {
        const int cb = (u & 1) * 32768;
        const char* pa0 = Lb + cb + arow + oA0;
        const char* pa1 = Lb + cb + arow + oA1;
        const char* pb0 = Lb + 65536 + cb + brow + oA0;
        const char* pb1 = Lb + 65536 + cb + brow + oA1;

        // ---- issue b0(4), a0(8), b1(4) ----
        #pragma unroll
        for (int j = 0; j < 2; ++j) {
            b0[j][0] = *(const bf16x8*)(pb0 + j * 2048);
            b0[j][1] = *(const bf16x8*)(pb1 + j * 2048);
        }
        #pragma unroll
        for (int i = 0; i < 4; ++i) {
            a0[i][0] = *(const bf16x8*)(pa0 + i * 2048);
            a0[i][1] = *(const bf16x8*)(pa1 + i * 2048);
        }
        #pragma unroll
        for (int j = 0; j < 2; ++j) {
            b1[j][0] = *(const bf16x8*)(pb0 + (2 + j) * 2048);
            b1[j][1] = *(const bf16x8*)(pb1 + (2 + j) * 2048);
        }
        __builtin_amdgcn_sched_barrier(0);

        // ---- stage next tile (other buffer) early: 8 gloads ----
        if (u + 1 < nt) {
            STAGE(u + 1, 0); STAGE(u + 1, 1); STAGE(u + 1, 2); STAGE(u + 1, 3);
        }
        __builtin_amdgcn_sched_barrier(0);

        // ---- Q00 after b0,a0 certified (b1 drains under it) ----
        LGKMC(4);
        __builtin_amdgcn_s_setprio(1);
        QUAD(a0, b0, 0, 0);
        __builtin_amdgcn_s_setprio(0);

        // ---- issue a1(8); Q01 after b1 certified (a1 drains under it) ----
        #pragma unroll
        for (int i = 0; i < 4; ++i) {
            a1[i][0] = *(const bf16x8*)(pa0 + (4 + i) * 2048);
            a1[i][1] = *(const bf16x8*)(pa1 + (4 + i) * 2048);
        }
        LGKMC(8);
        __builtin_amdgcn_s_setprio(1);
        QUAD(a0, b1, 0, 2);
        __builtin_amdgcn_s_setprio(0);

        // ---- Q11, Q10 after all reads certified ----
        LGKMC(0);
        __builtin_amdgcn_s_setprio(1);
        QUAD(a1, b1, 4, 2);
        QUAD(a1, b0, 4, 0);
        __builtin_amdgcn_s_setprio(0);

        // ---- tile boundary: stages (issued ~2300cyc ago) must be resident ----
        VMCNT(0);
        BARRIER;
    }

    // ---- epilogue: per-row max; cross-wave LDS reduce; one atomic/row ----
    float* red = (float*)L;   // [256][4]
    #pragma unroll
    for (int i = 0; i < 8; ++i) {
        #pragma unroll
        for (int rr = 0; rr < 4; ++rr) {
            float v = fmaxf(fmaxf(acc[i][0][rr], acc[i][1][rr]),
                            fmaxf(acc[i][2][rr], acc[i][3][rr]));
            v = fmaxf(v, __shfl_xor(v, 1));
            v = fmaxf(v, __shfl_xor(v, 2));
            v = fmaxf(v, __shfl_xor(v, 4));
            v = fmaxf(v, __shfl_xor(v, 8));
            if (l15 == 0) {
                int rloc = wr * 128 + i * 16 + l4 * 4 + rr;
                red[rloc * 4 + wc] = v;
            }
        }
    }
    __syncthreads();
    if (tid < 256) {
        float v = fmaxf(fmaxf(red[tid * 4 + 0], red[tid * 4 + 1]),
                        fmaxf(red[tid * 4 + 2], red[tid * 4 + 3]));
        atomicMax(&rowmax[n0 + tid], ordf(v));
    }
}

// ---------- kernel 3: BCE + novelty weight + mean ----------

__global__ __launch_bounds__(1024) void finalize_kernel(
    const float* __restrict__ pred, const float* __restrict__ targ,
    const u32* __restrict__ rowmax, float* __restrict__ out, int N)
{
    __shared__ float wsum[16];
    const int tid = threadIdx.x;
    const int lane = tid & 63;
    const int wid = tid >> 6;

    float sacc = 0.f;
    for (int i = tid; i < N; i += 1024) {
        float x = pred[i];
        float t = targ[i];
        float bl = fmaxf(x, 0.f) + log1pf(expf(-fabsf(x))) - x * t;  // softplus(x) - x*t
        float ms = unordf(rowmax[i]);
        float w = 1.0f + 2.0f * (1.0f - ms);
        sacc += bl * w;
    }
    #pragma unroll
    for (int m = 1; m <= 32; m <<= 1) sacc += __shfl_xor(sacc, m);
    if (lane == 0) wsum[wid] = sacc;
    __syncthreads();
    if (tid < 16) {
        float t = wsum[tid];
        t += __shfl_xor(t, 1);
        t += __shfl_xor(t, 2);
        t += __shfl_xor(t, 4);
        t += __shfl_xor(t, 8);
        if (tid == 0) out[0] = t / (float)N;
    }
}

// ---------- launch ----------

extern "C" void kernel_launch(void* const* d_in, const int* in_sizes, int n_in,
                              void* d_out, int out_size, void* d_ws, size_t ws_size,
                              hipStream_t stream) {
    const float* pred = (const float*)d_in[0];
    const float* targ = (const float*)d_in[1];
    const float* feat = (const float*)d_in[2];
    const float* memf = (const float*)d_in[3];
    const int N = in_sizes[0];
    const int D = in_sizes[2] / N;
    const int M = in_sizes[3] / D;
    float* out = (float*)d_out;

    u16* fb = (u16*)d_ws;                          // N*D bf16
    u16* mb = fb + (size_t)N * D;                  // M*D bf16
    u32* rowmax = (u32*)(mb + (size_t)M * D);      // N u32

    const int rows = N + M;
    norm_kernel<<<dim3((rows + 3) / 4), dim3(256), 0, stream>>>(
        feat, memf, fb, mb, rowmax, N, M, D);
    gemm_max_kernel<<<dim3(M / 256, N / 256), dim3(512), 0, stream>>>(
        fb, mb, rowmax, N, M, D);
    finalize_kernel<<<dim3(1), dim3(1024), 0, stream>>>(pred, targ, rowmax, out, N);
}

// Round 7
// 76.439 us; speedup vs baseline: 1.6032x; 1.3118x over previous
//
#include <hip/hip_runtime.h>
#include <math.h>

typedef unsigned char u8;
typedef unsigned short u16;
typedef unsigned int u32;
typedef __attribute__((ext_vector_type(8))) int i32x8;
typedef __attribute__((ext_vector_type(4))) float f32x4;

#define SC1 0x7F7F7F7F   // e8m0 scale bytes = 127 -> 2^0 = 1.0

// ---------- helpers ----------

// order-preserving float -> uint mapping (monotonic), for atomicMax on floats
__device__ __forceinline__ u32 ordf(float f) {
    u32 u = __float_as_uint(f);
    return (u & 0x80000000u) ? ~u : (u | 0x80000000u);
}
__device__ __forceinline__ float unordf(u32 u) {
    u = (u & 0x80000000u) ? (u & 0x7FFFFFFFu) : ~u;
    return __uint_as_float(u);
}

// f32 -> OCP e4m3fn with RNE. Assumes finite |x| <= 1.
__device__ __forceinline__ u32 f2e4m3(float x) {
    u32 u = __float_as_uint(x);
    u32 sgn = (u >> 24) & 0x80u;
    int ne = (int)((u >> 23) & 0xFF) - 120;   // e4m3 biased exponent
    if (ne >= 1) {
        u32 m = u & 0x7FFFFFu;
        u32 keep = m >> 20;
        u32 rest = m & 0xFFFFFu;
        keep += (rest > 0x80000u) || (rest == 0x80000u && (keep & 1u));
        if (keep == 8u) { keep = 0u; ne += 1; }
        return sgn | ((u32)ne << 3) | keep;
    }
    // subnormal: multiples of 2^-9
    float ax = __uint_as_float(u & 0x7FFFFFFFu);
    u32 f = (u32)__builtin_rintf(ax * 512.0f);
    if (f >= 8u) return sgn | 0x08u;          // rounds up to 2^-6 normal
    return sgn | f;
}

// async global->LDS, 16B per lane (dest = wave-uniform base + lane*16)
__device__ __forceinline__ void gload_lds16(const void* gsrc, void* ldst) {
    __builtin_amdgcn_global_load_lds(
        (const __attribute__((address_space(1))) void*)gsrc,
        (__attribute__((address_space(3))) void*)ldst,
        16, 0, 0);
}

__device__ __forceinline__ i32x8 ldfrag(const char* plo, const char* phi) {
    int4 lo = *(const int4*)plo;
    int4 hi = *(const int4*)phi;
    i32x8 r = {lo.x, lo.y, lo.z, lo.w, hi.x, hi.y, hi.z, hi.w};
    return r;
}

#define BARRIER do { __builtin_amdgcn_sched_barrier(0); \
                     __builtin_amdgcn_s_barrier(); \
                     __builtin_amdgcn_sched_barrier(0); } while (0)
#define VMCNT(n) do { asm volatile("s_waitcnt vmcnt(" #n ")" ::: "memory"); \
                      __builtin_amdgcn_sched_barrier(0); } while (0)
#define LGKMC(n) do { asm volatile("s_waitcnt lgkmcnt(" #n ")" ::: "memory"); \
                      __builtin_amdgcn_sched_barrier(0); } while (0)
#define SB0 __builtin_amdgcn_sched_barrier(0)

// ---------- kernel 1: normalize rows -> fp8 e4m3; init rowmax ----------
// one wave per row; lane handles 8 consecutive floats (D=512 = 64*8)

__global__ __launch_bounds__(256) void norm_kernel(
    const float* __restrict__ feat, const float* __restrict__ memf,
    u8* __restrict__ fb, u8* __restrict__ mb, u32* __restrict__ rowmax,
    int N, int M, int D)
{
    const int lane = threadIdx.x & 63;
    const int wid  = threadIdx.x >> 6;
    const int rid  = blockIdx.x * 4 + wid;
    if (rid >= N + M) return;

    const float* src;
    u8* dst;
    if (rid < N) { src = feat + (size_t)rid * D; dst = fb + (size_t)rid * D; }
    else         { src = memf + (size_t)(rid - N) * D; dst = mb + (size_t)(rid - N) * D; }

    float4 v0 = *(const float4*)(src + lane * 8);
    float4 v1 = *(const float4*)(src + lane * 8 + 4);
    float ss = v0.x*v0.x + v0.y*v0.y + v0.z*v0.z + v0.w*v0.w
             + v1.x*v1.x + v1.y*v1.y + v1.z*v1.z + v1.w*v1.w;
    #pragma unroll
    for (int m = 1; m <= 32; m <<= 1) ss += __shfl_xor(ss, m);

    float inv = 1.0f / fmaxf(sqrtf(ss), 1e-8f);

    u32 w0 =  f2e4m3(v0.x * inv)        | (f2e4m3(v0.y * inv) << 8)
           | (f2e4m3(v0.z * inv) << 16) | (f2e4m3(v0.w * inv) << 24);
    u32 w1 =  f2e4m3(v1.x * inv)        | (f2e4m3(v1.y * inv) << 8)
           | (f2e4m3(v1.z * inv) << 16) | (f2e4m3(v1.w * inv) << 24);
    *(uint2*)(dst + lane * 8) = make_uint2(w0, w1);

    if (rid < N && lane == 0) rowmax[rid] = 0u;   // below any real sim
}

// ---------- kernel 2: 256x256x(BK=128 fp8) MX-fp8 GEMM + fused row-max ----
// 8 waves (2M x 4N), per-wave 128x64 output = acc[8][4] 16x16 frags.
// MFMA: mfma_scale_f32_16x16x128_f8f6f4, fmt=0 (e4m3), scales = 1.0.
// LDS 128KB: A[2][256][128B] @0, B[2][256][128B] @64KB. Rows 128B, XOR
// swizzle byte ^= ((row&7)<<4) via pre-swizzled global source, linear dest.
// A-frag (16x16x128): lane l: row=l&15, k = (l>>4)*32 + [0..31] (32 contig
// bytes = 2 x b128). Per wave per tile: 16 A + 8 B = 24 b128 for K=128
// (half the bytes/FLOP of the bf16 version -> LDS wall moved).
// r6 skeleton: one barrier/tile; counted lgkm gates (issue order pinned by
// sched_barrier); stage u+1 early into other buffer; vmcnt(0) at boundary.

#define STAGEA(t, q) gload_lds16(gA + (size_t)(q) * 64 * D + (t) * 128, \
                                 &L[(((t) & 1) * 32768) + (q) * 8192 + tid * 16])
#define STAGEB(t, q) gload_lds16(gB + (size_t)(q) * 64 * D + (t) * 128, \
                                 &L[65536 + (((t) & 1) * 32768) + (q) * 8192 + tid * 16])
#define STAGE_ALL(t) do { STAGEA(t,0); STAGEA(t,1); STAGEA(t,2); STAGEA(t,3); \
                          STAGEB(t,0); STAGEB(t,1); STAGEB(t,2); STAGEB(t,3); } while (0)

// 4 M-frags x 2 N-frags, one K=128 MFMA each
#define QUAD(IO, J0) do { \
    _Pragma("unroll") \
    for (int i_ = 0; i_ < 4; ++i_) \
      _Pragma("unroll") \
      for (int j_ = 0; j_ < 2; ++j_) \
        acc[(IO) + i_][(J0) + j_] = __builtin_amdgcn_mfma_scale_f32_16x16x128_f8f6f4( \
            af[i_], bf[(J0) + j_], acc[(IO) + i_][(J0) + j_], 0, 0, 0, SC1, 0, SC1); \
  } while (0)

__global__ __launch_bounds__(512, 2) void gemm_max_kernel(
    const u8* __restrict__ fb, const u8* __restrict__ mb,
    u32* __restrict__ rowmax, int N, int M, int D)
{
    __shared__ __align__(16) u8 L[131072];   // 128 KB

    const int tid  = threadIdx.x;
    const int lane = tid & 63;
    const int wid  = tid >> 6;
    const int wr   = wid >> 2;      // 0..1
    const int wc   = wid & 3;       // 0..3
    const int l15  = lane & 15;
    const int l4   = lane >> 4;
    const int n0   = blockIdx.y * 256;
    const int m0   = blockIdx.x * 256;
    const int nt   = D >> 7;        // K-tiles of 128 (D=512 -> 4)

    // staging: per-thread pre-swizzled global bases (row = t8, chunk = tid&7)
    const int t8   = tid >> 3;
    const int swz  = ((tid & 7) ^ (t8 & 7)) * 16;
    const u8* gA = fb + (size_t)(n0 + t8) * D + swz;
    const u8* gB = mb + (size_t)(m0 + t8) * D + swz;

    // ds_read: per-lane swizzled k-offsets (two b128 per frag)
    const int s    = (l15 & 7) << 4;
    const int oLo  = (l4 * 32) ^ s;
    const int oHi  = (l4 * 32 + 16) ^ s;
    const int arowb = (wr * 128 + l15) * 128;   // byte row base in A space
    const int browb = (wc * 64 + l15) * 128;    // byte row base in B space
    const char* Lb = (const char*)L;

    f32x4 acc[8][4] = {};
    i32x8 af[4], bf[4];

    // ---- prologue: stage tile0, drain, barrier ----
    STAGE_ALL(0);
    VMCNT(0);
    BARRIER;

    for (int u = 0; u < nt; ++u) {
        const int cb = (u & 1) * 32768;
        const char* Ab = Lb + cb + arowb;
        const char* Bb = Lb + 65536 + cb + browb;

        // ---- issue a0 (8 reads) | b01 (4) | b23 (4), order pinned ----
        #pragma unroll
        for (int i = 0; i < 4; ++i)
            af[i] = ldfrag(Ab + i * 2048 + oLo, Ab + i * 2048 + oHi);
        SB0;
        #pragma unroll
        for (int j = 0; j < 2; ++j)
            bf[j] = ldfrag(Bb + j * 2048 + oLo, Bb + j * 2048 + oHi);
        SB0;
        #pragma unroll
        for (int j = 2; j < 4; ++j)
            bf[j] = ldfrag(Bb + j * 2048 + oLo, Bb + j * 2048 + oHi);
        SB0;

        // ---- stage next tile early (other buffer) ----
        if (u + 1 < nt) STAGE_ALL(u + 1);
        SB0;

        // ---- Q00 after a0,b01 certified (b23 drains under it) ----
        LGKMC(4);
        __builtin_amdgcn_s_setprio(1);
        QUAD(0, 0);
        __builtin_amdgcn_s_setprio(0);

        // ---- Q01 after b23 certified ----
        LGKMC(0);
        __builtin_amdgcn_s_setprio(1);
        QUAD(0, 2);
        __builtin_amdgcn_s_setprio(0);
        SB0;

        // ---- read a1 (reuses af regs), Q11, Q10 ----
        #pragma unroll
        for (int i = 0; i < 4; ++i)
            af[i] = ldfrag(Ab + (4 + i) * 2048 + oLo, Ab + (4 + i) * 2048 + oHi);
        LGKMC(0);
        __builtin_amdgcn_s_setprio(1);
        QUAD(4, 2);
        QUAD(4, 0);
        __builtin_amdgcn_s_setprio(0);

        // ---- tile boundary ----
        VMCNT(0);
        BARRIER;
    }

    // ---- epilogue: per-row max; cross-wave LDS reduce; one atomic/row ----
    float* red = (float*)L;   // [256][4]
    #pragma unroll
    for (int i = 0; i < 8; ++i) {
        #pragma unroll
        for (int rr = 0; rr < 4; ++rr) {
            float v = fmaxf(fmaxf(acc[i][0][rr], acc[i][1][rr]),
                            fmaxf(acc[i][2][rr], acc[i][3][rr]));
            v = fmaxf(v, __shfl_xor(v, 1));
            v = fmaxf(v, __shfl_xor(v, 2));
            v = fmaxf(v, __shfl_xor(v, 4));
            v = fmaxf(v, __shfl_xor(v, 8));
            if (l15 == 0) {
                int rloc = wr * 128 + i * 16 + l4 * 4 + rr;
                red[rloc * 4 + wc] = v;
            }
        }
    }
    __syncthreads();
    if (tid < 256) {
        float v = fmaxf(fmaxf(red[tid * 4 + 0], red[tid * 4 + 1]),
                        fmaxf(red[tid * 4 + 2], red[tid * 4 + 3]));
        atomicMax(&rowmax[n0 + tid], ordf(v));
    }
}

// ---------- kernel 3: BCE + novelty weight + mean ----------

__global__ __launch_bounds__(1024) void finalize_kernel(
    const float* __restrict__ pred, const float* __restrict__ targ,
    const u32* __restrict__ rowmax, float* __restrict__ out, int N)
{
    __shared__ float wsum[16];
    const int tid = threadIdx.x;
    const int lane = tid & 63;
    const int wid = tid >> 6;

    float sacc = 0.f;
    for (int i = tid; i < N; i += 1024) {
        float x = pred[i];
        float t = targ[i];
        float bl = fmaxf(x, 0.f) + log1pf(expf(-fabsf(x))) - x * t;  // softplus(x) - x*t
        float ms = unordf(rowmax[i]);
        float w = 1.0f + 2.0f * (1.0f - ms);
        sacc += bl * w;
    }
    #pragma unroll
    for (int m = 1; m <= 32; m <<= 1) sacc += __shfl_xor(sacc, m);
    if (lane == 0) wsum[wid] = sacc;
    __syncthreads();
    if (tid < 16) {
        float t = wsum[tid];
        t += __shfl_xor(t, 1);
        t += __shfl_xor(t, 2);
        t += __shfl_xor(t, 4);
        t += __shfl_xor(t, 8);
        if (tid == 0) out[0] = t / (float)N;
    }
}

// ---------- launch ----------

extern "C" void kernel_launch(void* const* d_in, const int* in_sizes, int n_in,
                              void* d_out, int out_size, void* d_ws, size_t ws_size,
                              hipStream_t stream) {
    const float* pred = (const float*)d_in[0];
    const float* targ = (const float*)d_in[1];
    const float* feat = (const float*)d_in[2];
    const float* memf = (const float*)d_in[3];
    const int N = in_sizes[0];
    const int D = in_sizes[2] / N;
    const int M = in_sizes[3] / D;
    float* out = (float*)d_out;

    u8* fb8 = (u8*)d_ws;                           // N*D fp8
    u8* mb8 = fb8 + (size_t)N * D;                 // M*D fp8
    u32* rowmax = (u32*)(mb8 + (size_t)M * D);     // N u32

    const int rows = N + M;
    norm_kernel<<<dim3((rows + 3) / 4), dim3(256), 0, stream>>>(
        feat, memf, fb8, mb8, rowmax, N, M, D);
    gemm_max_kernel<<<dim3(M / 256, N / 256), dim3(512), 0, stream>>>(
        fb8, mb8, rowmax, N, M, D);
    finalize_kernel<<<dim3(1), dim3(1024), 0, stream>>>(pred, targ, rowmax, out, N);
}